// Round 9
// baseline (334.146 us; speedup 1.0000x reference)
//
#include <hip/hip_runtime.h>
#include <math.h>

#define BB 4
#define SS 4096
#define DD 1024
#define DVV 1024
#define CHUNK 128
#define NCHUNK (SS/CHUNK)   // 32

typedef unsigned short u16;
typedef __bf16 bf16x8 __attribute__((ext_vector_type(8)));
typedef float f32x4 __attribute__((ext_vector_type(4)));
#define AS1 __attribute__((address_space(1)))
#define AS3 __attribute__((address_space(3)))
typedef AS3 char lds_char;

__device__ __forceinline__ u16 f2bf(float f) {
    union { float f; unsigned u; } v; v.f = f;
    unsigned r = (v.u + 0x7fffu + ((v.u >> 16) & 1u)) >> 16;
    return (u16)r;
}
__device__ __forceinline__ float bf2f(u16 h) {
    union { unsigned u; float f; } v; v.u = ((unsigned)h) << 16;
    return v.f;
}

// ================= fused prep kernel =================
__device__ __forceinline__ void transp_sec(const float* __restrict__ src, int src_ld,
                                           u16* __restrict__ dst, int dst_ld, int koff,
                                           int tb, float* sm) {
    int k0 = (tb & 31) * 32, n0 = (tb >> 5) * 32;
    int tx = threadIdx.x & 31, ty = threadIdx.x >> 5;
    #pragma unroll
    for (int i = 0; i < 32; i += 8)
        sm[(ty + i) * 33 + tx] = src[(size_t)(k0 + ty + i) * src_ld + n0 + tx];
    __syncthreads();
    #pragma unroll
    for (int i = 0; i < 32; i += 8)
        dst[(size_t)(n0 + ty + i) * dst_ld + koff + k0 + tx] = f2bf(sm[tx * 33 + ty + i]);
}

__global__ __launch_bounds__(256) void prep_k(const float* __restrict__ X,
                                              const float* __restrict__ vec,
                                              const float* __restrict__ values,
                                              const float* __restrict__ oper,
                                              const float* __restrict__ ff1,
                                              const float* __restrict__ ff1b,
                                              const float* __restrict__ ff2,
                                              u16* __restrict__ Vbf,
                                              u16* __restrict__ OpT,
                                              u16* __restrict__ FbT,
                                              u16* __restrict__ Bt1,
                                              u16* __restrict__ Bt2,
                                              float* __restrict__ csum,
                                              float* __restrict__ bias2) {
    __shared__ float sm[1056];
    int bid = blockIdx.x;
    int t = threadIdx.x;
    if (bid < 1024) {
        int g = bid * 256 + t;
        float4 v = *(const float4*)&values[(size_t)g * 4];
        u16* o = Vbf + (size_t)g * 4;
        o[0] = f2bf(v.x); o[1] = f2bf(v.y); o[2] = f2bf(v.z); o[3] = f2bf(v.w);
    } else if (bid < 2048) {
        transp_sec(oper, DD, OpT, 1024, 0, bid - 1024, sm);
    } else if (bid < 3072) {
        transp_sec(ff1 + (size_t)DD * DD, DD, FbT, 1024, 0, bid - 2048, sm);
    } else if (bid < 4096) {
        transp_sec(ff1, DD, Bt1, 2048, 0, bid - 3072, sm);
    } else if (bid < 5120) {
        transp_sec(ff2, DD, Bt2, 1024, 0, bid - 4096, sm);
    } else if (bid < 5248) {
        // chunk-sum of X, float4-vectorized: 128 blocks, 4 cols/thread (R8-verified)
        int g = (bid - 5120) * 256 + t;          // 32768
        int d = (g & 255) * 4;
        int c = (g >> 8) & (NCHUNK - 1);
        int b = g >> 13;
        const float* p = X + ((size_t)(b * SS + c * CHUNK)) * DD + d;
        float4 s = make_float4(0.f, 0.f, 0.f, 0.f);
        for (int tt = 0; tt < CHUNK; ++tt) {
            float4 x = *(const float4*)&p[(size_t)tt * DD];
            s.x += x.x; s.y += x.y; s.z += x.z; s.w += x.w;
        }
        *(float4*)&csum[((size_t)(b * NCHUNK + c)) * DD + d] = s;
    } else {
        int j0 = (bid - 5248) * 32;
        int j = t & 31, g = t >> 5;
        const float* fb = ff1 + (size_t)DD * DD;
        float s[4] = {0.f, 0.f, 0.f, 0.f};
        for (int dv = g * 128; dv < g * 128 + 128; ++dv) {
            float w = fb[(size_t)dv * DD + j0 + j];
            s[0] += vec[dv] * w;
            s[1] += vec[DVV + dv] * w;
            s[2] += vec[2 * DVV + dv] * w;
            s[3] += vec[3 * DVV + dv] * w;
        }
        #pragma unroll
        for (int b = 0; b < 4; ++b) sm[g * 128 + b * 32 + j] = s[b];
        __syncthreads();
        if (t < 128) {
            int jj = t & 31, b = t >> 5;
            float acc = ff1b[j0 + jj];
            #pragma unroll
            for (int gg = 0; gg < 8; ++gg) acc += sm[gg * 128 + b * 32 + jj];
            bias2[b * DD + j0 + jj] = acc;
        }
    }
}

// ================= 64x64 bf16 MFMA GEMM (device fn, sectioned) =================
__device__ __forceinline__ void mfma64_dev(const u16* __restrict__ Ag,
                                           const u16* __restrict__ Btg,
                                           u16* __restrict__ dst, int K,
                                           int dld, int koff, int bm, int bn) {
    __shared__ u16 Alds[64 * 32];
    __shared__ u16 Blds[64 * 32];
    f32x4 acc[2][2] = {};
    const int tid = threadIdx.x;
    const int wave = tid >> 6, lane = tid & 63;
    const int wm = wave & 1, wn = wave >> 1;
    const u16* ga = Ag + (size_t)(bm + (tid >> 2)) * K + (tid & 3) * 8;
    const u16* gb = Btg + (size_t)(bn + (tid >> 2)) * K + (tid & 3) * 8;
    const int lo = tid * 8;
    const int fk = (lane >> 4) * 8;
    for (int kt = 0; kt < K; kt += 32) {
        __builtin_amdgcn_global_load_lds((const AS1 void*)(ga + kt), (AS3 void*)(Alds + lo), 16, 0, 0);
        __builtin_amdgcn_global_load_lds((const AS1 void*)(gb + kt), (AS3 void*)(Blds + lo), 16, 0, 0);
        __syncthreads();
        bf16x8 af[2], bfr[2];
        #pragma unroll
        for (int i = 0; i < 2; ++i) af[i] = *(const bf16x8*)&Alds[(wm * 32 + i * 16 + (lane & 15)) * 32 + fk];
        #pragma unroll
        for (int i = 0; i < 2; ++i) bfr[i] = *(const bf16x8*)&Blds[(wn * 32 + i * 16 + (lane & 15)) * 32 + fk];
        #pragma unroll
        for (int mi = 0; mi < 2; ++mi)
            #pragma unroll
            for (int ni = 0; ni < 2; ++ni)
                acc[mi][ni] = __builtin_amdgcn_mfma_f32_16x16x32_bf16(af[mi], bfr[ni], acc[mi][ni], 0, 0, 0);
        __syncthreads();
    }
    #pragma unroll
    for (int mi = 0; mi < 2; ++mi)
        #pragma unroll
        for (int ni = 0; ni < 2; ++ni) {
            int col = bn + wn * 32 + ni * 16 + (lane & 15);
            #pragma unroll
            for (int r = 0; r < 4; ++r) {
                int row = bm + wm * 32 + mi * 16 + (lane >> 4) * 4 + r;
                dst[(size_t)row * dld + koff + col] = f2bf(acc[mi][ni][r]);
            }
        }
}

// k2: [0,16) exclusive chunk-prefix of csum ; [16,272) Wv = Vbf @ OpT^T
__global__ __launch_bounds__(256) void k2_k(float* __restrict__ csum,
                                            const u16* __restrict__ Vbf,
                                            const u16* __restrict__ OpT,
                                            u16* __restrict__ WvBf) {
    int bid = blockIdx.x;
    if (bid < 16) {
        int g = bid * 256 + threadIdx.x;
        int d = g & (DD - 1);
        int b = g >> 10;
        float* p = csum + ((size_t)b * NCHUNK) * DD + d;
        float run = 0.f;
        for (int c = 0; c < NCHUNK; ++c) {
            float v = p[(size_t)c * DD];
            p[(size_t)c * DD] = run;
            run += v;
        }
    } else {
        int t2 = bid - 16;
        mfma64_dev(Vbf, OpT, WvBf, 1024, 1024, 0, (t2 >> 4) * 64, (t2 & 15) * 64);
    }
}

// k3: [0,128) write Acat = [bf16(X) | bf16(prefix_mean)] (float4) ; [128,384) W2 -> Bt1 high
__global__ __launch_bounds__(256) void k3_k(const float* __restrict__ X,
                                            const float* __restrict__ csum,
                                            u16* __restrict__ Acat,
                                            const u16* __restrict__ FbT,
                                            const u16* __restrict__ WvBf,
                                            u16* __restrict__ Bt1) {
    int bid = blockIdx.x;
    if (bid < 128) {
        int g = bid * 256 + threadIdx.x;   // 32768; 4 cols/thread (R8-verified)
        int d = (g & 255) * 4;
        int c = (g >> 8) & (NCHUNK - 1);
        int b = g >> 13;
        size_t cs = ((size_t)(b * NCHUNK + c)) * DD + d;
        float4 run = *(const float4*)&csum[cs];
        const float* p = X + ((size_t)(b * SS + c * CHUNK)) * DD + d;
        u16* q = Acat + ((size_t)(b * SS + c * CHUNK)) * 2048 + d;
        int s0 = c * CHUNK;
        for (int t = 0; t < CHUNK; ++t) {
            float4 x = *(const float4*)&p[(size_t)t * DD];
            run.x += x.x; run.y += x.y; run.z += x.z; run.w += x.w;
            float inv = 1.0f / (float)(s0 + t + 1);
            ushort4 xa = make_ushort4(f2bf(x.x), f2bf(x.y), f2bf(x.z), f2bf(x.w));
            *(ushort4*)&q[(size_t)t * 2048] = xa;
            ushort4 ma = make_ushort4(f2bf(run.x * inv), f2bf(run.y * inv),
                                      f2bf(run.z * inv), f2bf(run.w * inv));
            *(ushort4*)&q[(size_t)t * 2048 + 1024] = ma;
        }
    } else {
        int t2 = bid - 128;
        mfma64_dev(FbT, WvBf, Bt1, 1024, 2048, 1024, (t2 >> 4) * 64, (t2 & 15) * 64);
    }
}

// ========== 256x256 8-phase bf16 MFMA GEMM core (exact R2 structure: proven best) =====
// 512 threads (8 waves: 2M x 4N), BK=64, 128 KiB LDS:
//   per buf (2): A rows[0,256)x64 @ {0, 16384}, B rows[0,256)x64 @ {32768, 49152}
// LDS swizzle: 16B-slot S ^= (row&7), pre-swizzled global source + swizzled ds_read.
// Fence discipline: barrier THEN lgkmcnt(0) THEN setprio+MFMA. Proven local optimum:
// frag-pipeline (R3), counted-lgkm (R4), bf0-keep (R5), staged-epi (R7) all regressed.
// vmcnt ledger: enter iter with 6 in flight {(t+1).A0,B1,A1}; +2 per phase; vmcnt(6)
// at P4-end lands tile (t+1) fully; 3 half-tiles stay in flight.
// NOTE (R8): ff1 here is an environment probe — identical code measured 68.9 (R2)
// and 81.5 (R8) with identical counters; cross-run drift, not a code effect.

template<int MH, int NH>
__device__ __forceinline__ void quad_mfma(f32x4 (&acc)[2][2][4][2],
                                          const bf16x8 (&af)[4][2],
                                          const bf16x8 (&bfr)[2][2]) {
#pragma unroll
    for (int mi = 0; mi < 4; ++mi)
#pragma unroll
        for (int ni = 0; ni < 2; ++ni) {
            acc[MH][NH][mi][ni] = __builtin_amdgcn_mfma_f32_16x16x32_bf16(af[mi][0], bfr[ni][0], acc[MH][NH][mi][ni], 0, 0, 0);
            acc[MH][NH][mi][ni] = __builtin_amdgcn_mfma_f32_16x16x32_bf16(af[mi][1], bfr[ni][1], acc[MH][NH][mi][ni], 0, 0, 0);
        }
}

__device__ __forceinline__ void read_af(bf16x8 (&af)[4][2], const lds_char* base, int sl0, int sl1) {
#pragma unroll
    for (int mi = 0; mi < 4; ++mi) {
        af[mi][0] = *(const AS3 bf16x8*)(base + mi * 2048 + sl0);
        af[mi][1] = *(const AS3 bf16x8*)(base + mi * 2048 + sl1);
    }
}
__device__ __forceinline__ void read_bf(bf16x8 (&bfr)[2][2], const lds_char* base, int sl0, int sl1) {
#pragma unroll
    for (int ni = 0; ni < 2; ++ni) {
        bfr[ni][0] = *(const AS3 bf16x8*)(base + ni * 2048 + sl0);
        bfr[ni][1] = *(const AS3 bf16x8*)(base + ni * 2048 + sl1);
    }
}

#define PH_MID do { asm volatile("" ::: "memory"); __builtin_amdgcn_s_barrier(); \
    asm volatile("s_waitcnt lgkmcnt(0)" ::: "memory"); __builtin_amdgcn_s_setprio(1); } while (0)
#define PH_END do { __builtin_amdgcn_s_setprio(0); asm volatile("" ::: "memory"); \
    __builtin_amdgcn_s_barrier(); asm volatile("" ::: "memory"); } while (0)
#define PH_END_VM do { __builtin_amdgcn_s_setprio(0); \
    asm volatile("s_waitcnt vmcnt(6)" ::: "memory"); \
    __builtin_amdgcn_s_barrier(); asm volatile("" ::: "memory"); } while (0)

__device__ __forceinline__ void mfma256_core(const u16* __restrict__ Ag, int lda,
                                             const u16* __restrict__ Btg, int ldb,
                                             int K, int bm, int bn, lds_char* ldsb,
                                             f32x4 (&acc)[2][2][4][2]) {
    const int tid = threadIdx.x;
    const int lane = tid & 63, wave = tid >> 6;
    const int wm = wave >> 2, wn = wave & 3;
    const int q = lane >> 4;
    const int nkt = K >> 6;

    // ---- staging source pointers (pre-swizzled global addresses) ----
    const int rl = tid >> 3, Ss = tid & 7;
    const int swoff = (Ss ^ (rl & 7)) * 8;            // swizzled 8-elem slot
    const u16* pA0 = Ag + (size_t)(bm + rl) * lda + swoff;
    const u16* pA1 = pA0 + (size_t)128 * lda;
    const u16* pB0 = Btg + (size_t)(bn + rl) * ldb + swoff;
    const u16* pB1 = pB0 + (size_t)128 * ldb;
    const size_t dA = (size_t)64 * lda, dB = (size_t)64 * ldb;
    const int dst = tid * 16;

#define STG(P, DLT, RGN, ST) do { \
    const u16* _g = (P) + (size_t)(ST) * 64; \
    __builtin_amdgcn_global_load_lds((const AS1 void*)_g, (AS3 void*)(ldsb + (RGN) + dst), 16, 0, 0); \
    __builtin_amdgcn_global_load_lds((const AS1 void*)(_g + (DLT)), (AS3 void*)(ldsb + (RGN) + 8192 + dst), 16, 0, 0); \
} while (0)

    // ---- fragment read offsets (swizzled) ----
    const int arow = (wm * 64 + (lane & 15)) * 128;           // A row byte (within A half)
    const int brow = (wn * 32 + (lane & 15)) * 128 + 32768;   // B row byte (B0 region base)
    const int swz = lane & 7;
    const int sl0 = (q ^ swz) << 4;        // ks=0 slot byte
    const int sl1 = ((4 + q) ^ swz) << 4;  // ks=1 slot byte

    bf16x8 af[4][2], bfr[2][2];

    // ---- prologue: t0.A0, t0.B1, t0.A1, t0.B0, t1.A0, t1.B1, t1.A1 (14 loads) ----
    STG(pA0, dA, 0, 0);
    STG(pB1, dB, 49152, 0);
    STG(pA1, dA, 16384, 0);
    STG(pB0, dB, 32768, 0);
    STG(pA0, dA, 65536 + 0, 1);
    STG(pB1, dB, 65536 + 49152, 1);
    STG(pA1, dA, 65536 + 16384, 1);
    asm volatile("s_waitcnt vmcnt(6)" ::: "memory");   // tile0 fully landed
    __builtin_amdgcn_s_barrier();
    asm volatile("" ::: "memory");

    for (int t = 0; t < nkt; ++t) {
        const int bufb = (t & 1) << 16;
        int st1 = t + 1; if (st1 == nkt) st1 = 0;
        int st2 = t + 2; if (st2 >= nkt) st2 -= nkt;
        const lds_char* Lb = ldsb + bufb;

        // ---- phase 1: quad(0,0) — 12 ds_reads; stage (t+1).B0 -> other buf ----
        read_af(af, Lb + arow, sl0, sl1);
        read_bf(bfr, Lb + brow, sl0, sl1);
        STG(pB0, dB, (bufb ^ 65536) + 32768, st1);
        PH_MID;
        quad_mfma<0, 0>(acc, af, bfr);
        PH_END;

        // ---- phase 2: quad(0,1) — stage (t+2).A0 into A0 (freed at phase 1) ----
        read_bf(bfr, Lb + brow + 16384, sl0, sl1);
        STG(pA0, dA, bufb + 0, st2);
        PH_MID;
        quad_mfma<0, 1>(acc, af, bfr);
        PH_END;

        // ---- phase 3: quad(1,1) — stage (t+2).B1 into B1 (freed at phase 2) ----
        read_af(af, Lb + arow + 16384, sl0, sl1);
        STG(pB1, dB, bufb + 49152, st2);
        PH_MID;
        quad_mfma<1, 1>(acc, af, bfr);
        PH_END;

        // ---- phase 4: quad(1,0) — stage (t+2).A1 into A1 (freed at phase 3) ----
        read_bf(bfr, Lb + brow, sl0, sl1);
        STG(pA1, dA, bufb + 16384, st2);
        PH_MID;
        quad_mfma<1, 0>(acc, af, bfr);
        PH_END_VM;   // vmcnt(6): (t+1) fully landed; 3 half-tiles in flight
    }
    asm volatile("s_waitcnt vmcnt(0)" ::: "memory");   // drain before LDS teardown
#undef STG
}

// hidden = relu(Acat @ Bt1^T + bias2[b]) -> bf16  (exact R2 kernel)
__global__ __launch_bounds__(512, 2) void mfma_ff1_k(const u16* __restrict__ Acat,
                                                     const u16* __restrict__ Bt1,
                                                     const float* __restrict__ bias2,
                                                     u16* __restrict__ H) {
    __shared__ __align__(16) char lds[131072];
    f32x4 acc[2][2][4][2] = {};
    int bid = blockIdx.x;                 // 256 blocks, nwg%8==0 -> bijective XCD swizzle
    int x = bid & 7, j = bid >> 3;
    int nt = j & 3, mt = (j >> 2) * 8 + x;
    int bm = mt * 256, bn = nt * 256;
    mfma256_core(Acat, 2048, Bt1, 2048, 2048, bm, bn, (lds_char*)lds, acc);
    const int lane = threadIdx.x & 63, wave = threadIdx.x >> 6;
    const int wm = wave >> 2, wn = wave & 3;
    int rbase = bm + wm * 64 + (lane >> 4) * 4;
    int cbase = bn + wn * 32 + (lane & 15);
    int bb = bm >> 12;
#pragma unroll
    for (int mh = 0; mh < 2; ++mh)
#pragma unroll
        for (int nh = 0; nh < 2; ++nh)
#pragma unroll
            for (int mi = 0; mi < 4; ++mi)
#pragma unroll
                for (int ni = 0; ni < 2; ++ni) {
                    int col = cbase + nh * 128 + ni * 16;
                    float bz = bias2[bb * 1024 + col];
                    int row0 = rbase + mh * 128 + mi * 16;
#pragma unroll
                    for (int r = 0; r < 4; ++r) {
                        float v = acc[mh][nh][mi][ni][r] + bz;
                        H[(size_t)(row0 + r) * 1024 + col] = f2bf(fmaxf(v, 0.f));
                    }
                }
}

// P = H @ ff2 + ff2_bias + X(fp32) -> bf16 (exact R2 kernel; P aliases Acat)
__global__ __launch_bounds__(512, 2) void mfma_ff2_k(const u16* __restrict__ H,
                                                     const u16* __restrict__ Bt2,
                                                     const float* __restrict__ ff2b,
                                                     const float* __restrict__ X,
                                                     u16* __restrict__ P) {
    __shared__ __align__(16) char lds[131072];
    f32x4 acc[2][2][4][2] = {};
    int bid = blockIdx.x;
    int x = bid & 7, j = bid >> 3;
    int nt = j & 3, mt = (j >> 2) * 8 + x;
    int bm = mt * 256, bn = nt * 256;
    mfma256_core(H, 1024, Bt2, 1024, 1024, bm, bn, (lds_char*)lds, acc);
    const int lane = threadIdx.x & 63, wave = threadIdx.x >> 6;
    const int wm = wave >> 2, wn = wave & 3;
    int rbase = bm + wm * 64 + (lane >> 4) * 4;
    int cbase = bn + wn * 32 + (lane & 15);
#pragma unroll
    for (int mh = 0; mh < 2; ++mh)
#pragma unroll
        for (int nh = 0; nh < 2; ++nh)
#pragma unroll
            for (int mi = 0; mi < 4; ++mi)
#pragma unroll
                for (int ni = 0; ni < 2; ++ni) {
                    int col = cbase + nh * 128 + ni * 16;
                    float bz = ff2b[col];
                    int row0 = rbase + mh * 128 + mi * 16;
#pragma unroll
                    for (int r = 0; r < 4; ++r) {
                        size_t off = (size_t)(row0 + r) * 1024 + col;
                        P[off] = f2bf(acc[mh][nh][mi][ni][r] + bz + X[off]);
                    }
                }
}

// ================= LayerNorm over bf16 P -> fp32 out (exact R2 kernel) =================
__global__ __launch_bounds__(256) void ln_k(const u16* __restrict__ P,
                                            const float* __restrict__ gam,
                                            const float* __restrict__ bet,
                                            float* __restrict__ out) {
    __shared__ float sbuf[4];
    int row = blockIdx.x;
    int tid = threadIdx.x;
    const u16* pr = P + (size_t)row * DD + tid * 4;
    float x0 = bf2f(pr[0]), x1 = bf2f(pr[1]), x2 = bf2f(pr[2]), x3 = bf2f(pr[3]);
    float local = x0 + x1 + x2 + x3;
    #pragma unroll
    for (int o = 32; o > 0; o >>= 1) local += __shfl_down(local, o, 64);
    if ((tid & 63) == 0) sbuf[tid >> 6] = local;
    __syncthreads();
    float mu = (sbuf[0] + sbuf[1] + sbuf[2] + sbuf[3]) * (1.0f / 1024.0f);
    __syncthreads();
    float d0 = x0 - mu, d1 = x1 - mu, d2 = x2 - mu, d3 = x3 - mu;
    float v2 = d0 * d0 + d1 * d1 + d2 * d2 + d3 * d3;
    #pragma unroll
    for (int o = 32; o > 0; o >>= 1) v2 += __shfl_down(v2, o, 64);
    if ((tid & 63) == 0) sbuf[tid >> 6] = v2;
    __syncthreads();
    float var = (sbuf[0] + sbuf[1] + sbuf[2] + sbuf[3]) * (1.0f / 1024.0f);
    float rs = rsqrtf(var + 1e-6f);
    float4 gg = *(const float4*)&gam[tid * 4];
    float4 bb = *(const float4*)&bet[tid * 4];
    float4 o4;
    o4.x = d0 * rs * gg.x + bb.x;
    o4.y = d1 * rs * gg.y + bb.y;
    o4.z = d2 * rs * gg.z + bb.z;
    o4.w = d3 * rs * gg.w + bb.w;
    *(float4*)&out[(size_t)row * DD + tid * 4] = o4;
}

extern "C" void kernel_launch(void* const* d_in, const int* in_sizes, int n_in,
                              void* d_out, int out_size, void* d_ws, size_t ws_size,
                              hipStream_t stream) {
    const float* X      = (const float*)d_in[0];
    const float* vec    = (const float*)d_in[1];
    // d_in[2] attention_weights, d_in[3] temperature: numerically dead (eps=1e-30 rounds away in fp32)
    const float* values = (const float*)d_in[4];
    const float* oper   = (const float*)d_in[5];
    const float* ff1    = (const float*)d_in[6];
    const float* ff1b   = (const float*)d_in[7];
    const float* ff2    = (const float*)d_in[8];
    const float* ff2b   = (const float*)d_in[9];
    const float* gam    = (const float*)d_in[10];
    const float* bet    = (const float*)d_in[11];
    float* out = (float*)d_out;

    char* w = (char*)d_ws;
    u16*   Acat  = (u16*)w;                                  // 64 MB (16384x2048)
    u16*   Pbf   = (u16*)w;                                  // alias: Acat dead when P written
    u16*   Hbf   = (u16*)(w + (size_t)(64u << 20));          // 32 MB
    u16*   Vbf   = (u16*)(w + (size_t)(96u << 20));          // 2 MB
    u16*   OpT   = (u16*)(w + (size_t)(98u << 20));          // 2 MB
    u16*   FbT   = (u16*)(w + (size_t)(100u << 20));         // 2 MB
    u16*   WvBf  = (u16*)(w + (size_t)(102u << 20));         // 2 MB
    u16*   Bt1   = (u16*)(w + (size_t)(104u << 20));         // 4 MB (1024x2048)
    u16*   Bt2   = (u16*)(w + (size_t)(108u << 20));         // 2 MB
    float* bias2 = (float*)(w + (size_t)(110u << 20));       // 16 KB
    float* csum  = (float*)(w + (size_t)(110u << 20) + (1u << 16)); // 512 KB

    // 1) fused prep: converts, transposes, chunk_sum (f4), bias2
    prep_k<<<5280, 256, 0, stream>>>(X, vec, values, oper, ff1, ff1b, ff2,
                                     Vbf, OpT, FbT, Bt1, Bt2, csum, bias2);
    // 2) chunk-prefix || Wv = values @ operator
    k2_k<<<272, 256, 0, stream>>>(csum, Vbf, OpT, WvBf);
    // 3) Acat pack (f4) || W2 -> Bt1 high half
    k3_k<<<384, 256, 0, stream>>>(X, csum, Acat, FbT, WvBf, Bt1);
    // 4) hidden = relu([X|M] @ [W1;W2]^T + bias2)  — exact R2 GEMM (environment probe)
    mfma_ff1_k<<<256, 512, 0, stream>>>(Acat, Bt1, bias2, Hbf);
    // 5) P = hidden @ ff2^T + ff2b + X             — exact R2 GEMM (X back in epilogue)
    mfma_ff2_k<<<256, 512, 0, stream>>>(Hbf, Bt2, ff2b, X, Pbf);
    // 6) LayerNorm
    ln_k<<<BB * SS, 256, 0, stream>>>(Pbf, gam, bet, out);
}

// Round 10
// 311.480 us; speedup vs baseline: 1.0728x; 1.0728x over previous
//
#include <hip/hip_runtime.h>
#include <math.h>

#define BB 4
#define SS 4096
#define DD 1024
#define DVV 1024
#define CHUNK 128
#define NCHUNK (SS/CHUNK)   // 32

typedef unsigned short u16;
typedef __bf16 bf16x8 __attribute__((ext_vector_type(8)));
typedef float f32x4 __attribute__((ext_vector_type(4)));
#define AS1 __attribute__((address_space(1)))
#define AS3 __attribute__((address_space(3)))
typedef AS3 char lds_char;

__device__ __forceinline__ u16 f2bf(float f) {
    union { float f; unsigned u; } v; v.f = f;
    unsigned r = (v.u + 0x7fffu + ((v.u >> 16) & 1u)) >> 16;
    return (u16)r;
}
__device__ __forceinline__ float bf2f(u16 h) {
    union { unsigned u; float f; } v; v.u = ((unsigned)h) << 16;
    return v.f;
}

// ================= fused prep kernel =================
__device__ __forceinline__ void transp_sec(const float* __restrict__ src, int src_ld,
                                           u16* __restrict__ dst, int dst_ld, int koff,
                                           int tb, float* sm) {
    int k0 = (tb & 31) * 32, n0 = (tb >> 5) * 32;
    int tx = threadIdx.x & 31, ty = threadIdx.x >> 5;
    #pragma unroll
    for (int i = 0; i < 32; i += 8)
        sm[(ty + i) * 33 + tx] = src[(size_t)(k0 + ty + i) * src_ld + n0 + tx];
    __syncthreads();
    #pragma unroll
    for (int i = 0; i < 32; i += 8)
        dst[(size_t)(n0 + ty + i) * dst_ld + koff + k0 + tx] = f2bf(sm[tx * 33 + ty + i]);
}

__global__ __launch_bounds__(256) void prep_k(const float* __restrict__ X,
                                              const float* __restrict__ vec,
                                              const float* __restrict__ values,
                                              const float* __restrict__ oper,
                                              const float* __restrict__ ff1,
                                              const float* __restrict__ ff1b,
                                              const float* __restrict__ ff2,
                                              u16* __restrict__ Vbf,
                                              u16* __restrict__ OpT,
                                              u16* __restrict__ FbT,
                                              u16* __restrict__ Bt1,
                                              u16* __restrict__ Bt2,
                                              float* __restrict__ csum,
                                              float* __restrict__ bias2) {
    __shared__ float sm[1056];
    int bid = blockIdx.x;
    int t = threadIdx.x;
    if (bid < 1024) {
        int g = bid * 256 + t;
        float4 v = *(const float4*)&values[(size_t)g * 4];
        u16* o = Vbf + (size_t)g * 4;
        o[0] = f2bf(v.x); o[1] = f2bf(v.y); o[2] = f2bf(v.z); o[3] = f2bf(v.w);
    } else if (bid < 2048) {
        transp_sec(oper, DD, OpT, 1024, 0, bid - 1024, sm);
    } else if (bid < 3072) {
        transp_sec(ff1 + (size_t)DD * DD, DD, FbT, 1024, 0, bid - 2048, sm);
    } else if (bid < 4096) {
        transp_sec(ff1, DD, Bt1, 2048, 0, bid - 3072, sm);
    } else if (bid < 5120) {
        transp_sec(ff2, DD, Bt2, 1024, 0, bid - 4096, sm);
    } else if (bid < 5632) {
        // scalar chunk-sum (R9 showed f4/128-block variant costs ~20us: TLP loss)
        int g = (bid - 5120) * 256 + t;
        int d = g & (DD - 1);
        int c = (g >> 10) & (NCHUNK - 1);
        int b = g >> 15;
        const float* p = X + ((size_t)(b * SS + c * CHUNK)) * DD + d;
        float s = 0.f;
        for (int tt = 0; tt < CHUNK; ++tt) s += p[(size_t)tt * DD];
        csum[g] = s;
    } else {
        int j0 = (bid - 5632) * 32;
        int j = t & 31, g = t >> 5;
        const float* fb = ff1 + (size_t)DD * DD;
        float s[4] = {0.f, 0.f, 0.f, 0.f};
        for (int dv = g * 128; dv < g * 128 + 128; ++dv) {
            float w = fb[(size_t)dv * DD + j0 + j];
            s[0] += vec[dv] * w;
            s[1] += vec[DVV + dv] * w;
            s[2] += vec[2 * DVV + dv] * w;
            s[3] += vec[3 * DVV + dv] * w;
        }
        #pragma unroll
        for (int b = 0; b < 4; ++b) sm[g * 128 + b * 32 + j] = s[b];
        __syncthreads();
        if (t < 128) {
            int jj = t & 31, b = t >> 5;
            float acc = ff1b[j0 + jj];
            #pragma unroll
            for (int gg = 0; gg < 8; ++gg) acc += sm[gg * 128 + b * 32 + jj];
            bias2[b * DD + j0 + jj] = acc;
        }
    }
}

// ================= 64x64 bf16 MFMA GEMM (device fn, sectioned) =================
__device__ __forceinline__ void mfma64_dev(const u16* __restrict__ Ag,
                                           const u16* __restrict__ Btg,
                                           u16* __restrict__ dst, int K,
                                           int dld, int koff, int bm, int bn) {
    __shared__ u16 Alds[64 * 32];
    __shared__ u16 Blds[64 * 32];
    f32x4 acc[2][2] = {};
    const int tid = threadIdx.x;
    const int wave = tid >> 6, lane = tid & 63;
    const int wm = wave & 1, wn = wave >> 1;
    const u16* ga = Ag + (size_t)(bm + (tid >> 2)) * K + (tid & 3) * 8;
    const u16* gb = Btg + (size_t)(bn + (tid >> 2)) * K + (tid & 3) * 8;
    const int lo = tid * 8;
    const int fk = (lane >> 4) * 8;
    for (int kt = 0; kt < K; kt += 32) {
        __builtin_amdgcn_global_load_lds((const AS1 void*)(ga + kt), (AS3 void*)(Alds + lo), 16, 0, 0);
        __builtin_amdgcn_global_load_lds((const AS1 void*)(gb + kt), (AS3 void*)(Blds + lo), 16, 0, 0);
        __syncthreads();
        bf16x8 af[2], bfr[2];
        #pragma unroll
        for (int i = 0; i < 2; ++i) af[i] = *(const bf16x8*)&Alds[(wm * 32 + i * 16 + (lane & 15)) * 32 + fk];
        #pragma unroll
        for (int i = 0; i < 2; ++i) bfr[i] = *(const bf16x8*)&Blds[(wn * 32 + i * 16 + (lane & 15)) * 32 + fk];
        #pragma unroll
        for (int mi = 0; mi < 2; ++mi)
            #pragma unroll
            for (int ni = 0; ni < 2; ++ni)
                acc[mi][ni] = __builtin_amdgcn_mfma_f32_16x16x32_bf16(af[mi], bfr[ni], acc[mi][ni], 0, 0, 0);
        __syncthreads();
    }
    #pragma unroll
    for (int mi = 0; mi < 2; ++mi)
        #pragma unroll
        for (int ni = 0; ni < 2; ++ni) {
            int col = bn + wn * 32 + ni * 16 + (lane & 15);
            #pragma unroll
            for (int r = 0; r < 4; ++r) {
                int row = bm + wm * 32 + mi * 16 + (lane >> 4) * 4 + r;
                dst[(size_t)row * dld + koff + col] = f2bf(acc[mi][ni][r]);
            }
        }
}

// k2: [0,16) exclusive chunk-prefix of csum ; [16,272) Wv = Vbf @ OpT^T
__global__ __launch_bounds__(256) void k2_k(float* __restrict__ csum,
                                            const u16* __restrict__ Vbf,
                                            const u16* __restrict__ OpT,
                                            u16* __restrict__ WvBf) {
    int bid = blockIdx.x;
    if (bid < 16) {
        int g = bid * 256 + threadIdx.x;
        int d = g & (DD - 1);
        int b = g >> 10;
        float* p = csum + ((size_t)b * NCHUNK) * DD + d;
        float run = 0.f;
        for (int c = 0; c < NCHUNK; ++c) {
            float v = p[(size_t)c * DD];
            p[(size_t)c * DD] = run;
            run += v;
        }
    } else {
        int t2 = bid - 16;
        mfma64_dev(Vbf, OpT, WvBf, 1024, 1024, 0, (t2 >> 4) * 64, (t2 & 15) * 64);
    }
}

// k3: [0,256) write Acat = [bf16(X) | bf16(prefix_mean)] ; [256,512) W2 -> Bt1 high half
__global__ __launch_bounds__(256) void k3_k(const float* __restrict__ X,
                                            const float* __restrict__ csum,
                                            u16* __restrict__ Acat,
                                            const u16* __restrict__ FbT,
                                            const u16* __restrict__ WvBf,
                                            u16* __restrict__ Bt1) {
    int bid = blockIdx.x;
    if (bid < 256) {
        int g = bid * 256 + threadIdx.x;   // 65536; 2 cols/thread (R2-proven; f4 regressed)
        int d = (g & 511) * 2;
        int c = (g >> 9) & (NCHUNK - 1);
        int b = g >> 14;
        size_t cs = ((size_t)(b * NCHUNK + c)) * DD + d;
        float run0 = csum[cs], run1 = csum[cs + 1];
        const float* p = X + ((size_t)(b * SS + c * CHUNK)) * DD + d;
        u16* q = Acat + ((size_t)(b * SS + c * CHUNK)) * 2048 + d;
        int s0 = c * CHUNK;
        for (int t = 0; t < CHUNK; ++t) {
            float2 x = *(const float2*)&p[(size_t)t * DD];
            run0 += x.x; run1 += x.y;
            float inv = 1.0f / (float)(s0 + t + 1);
            *(ushort2*)&q[(size_t)t * 2048] = make_ushort2(f2bf(x.x), f2bf(x.y));
            *(ushort2*)&q[(size_t)t * 2048 + 1024] = make_ushort2(f2bf(run0 * inv), f2bf(run1 * inv));
        }
    } else {
        int t2 = bid - 256;
        mfma64_dev(FbT, WvBf, Bt1, 1024, 2048, 1024, (t2 >> 4) * 64, (t2 & 15) * 64);
    }
}

// ========== 256x256 8-phase bf16 MFMA GEMM core (exact R2 structure: 312us best) =====
// 512 threads (8 waves: 2M x 4N), BK=64, 128 KiB LDS:
//   per buf (2): A rows[0,256)x64 @ {0, 16384}, B rows[0,256)x64 @ {32768, 49152}
// LDS swizzle: 16B-slot S ^= (row&7), pre-swizzled global source + swizzled ds_read.
// Fence discipline: barrier THEN lgkmcnt(0) THEN setprio+MFMA. Proven local optimum:
// frag-pipeline (R3), counted-lgkm (R4), bf0-keep (R5), staged-epi (R7) all regressed.
// vmcnt ledger: enter iter with 6 in flight {(t+1).A0,B1,A1}; +2 per phase; vmcnt(6)
// at P4-end lands tile (t+1) fully; 3 half-tiles stay in flight.

template<int MH, int NH>
__device__ __forceinline__ void quad_mfma(f32x4 (&acc)[2][2][4][2],
                                          const bf16x8 (&af)[4][2],
                                          const bf16x8 (&bfr)[2][2]) {
#pragma unroll
    for (int mi = 0; mi < 4; ++mi)
#pragma unroll
        for (int ni = 0; ni < 2; ++ni) {
            acc[MH][NH][mi][ni] = __builtin_amdgcn_mfma_f32_16x16x32_bf16(af[mi][0], bfr[ni][0], acc[MH][NH][mi][ni], 0, 0, 0);
            acc[MH][NH][mi][ni] = __builtin_amdgcn_mfma_f32_16x16x32_bf16(af[mi][1], bfr[ni][1], acc[MH][NH][mi][ni], 0, 0, 0);
        }
}

__device__ __forceinline__ void read_af(bf16x8 (&af)[4][2], const lds_char* base, int sl0, int sl1) {
#pragma unroll
    for (int mi = 0; mi < 4; ++mi) {
        af[mi][0] = *(const AS3 bf16x8*)(base + mi * 2048 + sl0);
        af[mi][1] = *(const AS3 bf16x8*)(base + mi * 2048 + sl1);
    }
}
__device__ __forceinline__ void read_bf(bf16x8 (&bfr)[2][2], const lds_char* base, int sl0, int sl1) {
#pragma unroll
    for (int ni = 0; ni < 2; ++ni) {
        bfr[ni][0] = *(const AS3 bf16x8*)(base + ni * 2048 + sl0);
        bfr[ni][1] = *(const AS3 bf16x8*)(base + ni * 2048 + sl1);
    }
}

#define PH_MID do { asm volatile("" ::: "memory"); __builtin_amdgcn_s_barrier(); \
    asm volatile("s_waitcnt lgkmcnt(0)" ::: "memory"); __builtin_amdgcn_s_setprio(1); } while (0)
#define PH_END do { __builtin_amdgcn_s_setprio(0); asm volatile("" ::: "memory"); \
    __builtin_amdgcn_s_barrier(); asm volatile("" ::: "memory"); } while (0)
#define PH_END_VM do { __builtin_amdgcn_s_setprio(0); \
    asm volatile("s_waitcnt vmcnt(6)" ::: "memory"); \
    __builtin_amdgcn_s_barrier(); asm volatile("" ::: "memory"); } while (0)

__device__ __forceinline__ void mfma256_core(const u16* __restrict__ Ag, int lda,
                                             const u16* __restrict__ Btg, int ldb,
                                             int K, int bm, int bn, lds_char* ldsb,
                                             f32x4 (&acc)[2][2][4][2]) {
    const int tid = threadIdx.x;
    const int lane = tid & 63, wave = tid >> 6;
    const int wm = wave >> 2, wn = wave & 3;
    const int q = lane >> 4;
    const int nkt = K >> 6;

    // ---- staging source pointers (pre-swizzled global addresses) ----
    const int rl = tid >> 3, Ss = tid & 7;
    const int swoff = (Ss ^ (rl & 7)) * 8;            // swizzled 8-elem slot
    const u16* pA0 = Ag + (size_t)(bm + rl) * lda + swoff;
    const u16* pA1 = pA0 + (size_t)128 * lda;
    const u16* pB0 = Btg + (size_t)(bn + rl) * ldb + swoff;
    const u16* pB1 = pB0 + (size_t)128 * ldb;
    const size_t dA = (size_t)64 * lda, dB = (size_t)64 * ldb;
    const int dst = tid * 16;

#define STG(P, DLT, RGN, ST) do { \
    const u16* _g = (P) + (size_t)(ST) * 64; \
    __builtin_amdgcn_global_load_lds((const AS1 void*)_g, (AS3 void*)(ldsb + (RGN) + dst), 16, 0, 0); \
    __builtin_amdgcn_global_load_lds((const AS1 void*)(_g + (DLT)), (AS3 void*)(ldsb + (RGN) + 8192 + dst), 16, 0, 0); \
} while (0)

    // ---- fragment read offsets (swizzled) ----
    const int arow = (wm * 64 + (lane & 15)) * 128;           // A row byte (within A half)
    const int brow = (wn * 32 + (lane & 15)) * 128 + 32768;   // B row byte (B0 region base)
    const int swz = lane & 7;
    const int sl0 = (q ^ swz) << 4;        // ks=0 slot byte
    const int sl1 = ((4 + q) ^ swz) << 4;  // ks=1 slot byte

    bf16x8 af[4][2], bfr[2][2];

    // ---- prologue: t0.A0, t0.B1, t0.A1, t0.B0, t1.A0, t1.B1, t1.A1 (14 loads) ----
    STG(pA0, dA, 0, 0);
    STG(pB1, dB, 49152, 0);
    STG(pA1, dA, 16384, 0);
    STG(pB0, dB, 32768, 0);
    STG(pA0, dA, 65536 + 0, 1);
    STG(pB1, dB, 65536 + 49152, 1);
    STG(pA1, dA, 65536 + 16384, 1);
    asm volatile("s_waitcnt vmcnt(6)" ::: "memory");   // tile0 fully landed
    __builtin_amdgcn_s_barrier();
    asm volatile("" ::: "memory");

    for (int t = 0; t < nkt; ++t) {
        const int bufb = (t & 1) << 16;
        int st1 = t + 1; if (st1 == nkt) st1 = 0;
        int st2 = t + 2; if (st2 >= nkt) st2 -= nkt;
        const lds_char* Lb = ldsb + bufb;

        // ---- phase 1: quad(0,0) — 12 ds_reads; stage (t+1).B0 -> other buf ----
        read_af(af, Lb + arow, sl0, sl1);
        read_bf(bfr, Lb + brow, sl0, sl1);
        STG(pB0, dB, (bufb ^ 65536) + 32768, st1);
        PH_MID;
        quad_mfma<0, 0>(acc, af, bfr);
        PH_END;

        // ---- phase 2: quad(0,1) — stage (t+2).A0 into A0 (freed at phase 1) ----
        read_bf(bfr, Lb + brow + 16384, sl0, sl1);
        STG(pA0, dA, bufb + 0, st2);
        PH_MID;
        quad_mfma<0, 1>(acc, af, bfr);
        PH_END;

        // ---- phase 3: quad(1,1) — stage (t+2).B1 into B1 (freed at phase 2) ----
        read_af(af, Lb + arow + 16384, sl0, sl1);
        STG(pB1, dB, bufb + 49152, st2);
        PH_MID;
        quad_mfma<1, 1>(acc, af, bfr);
        PH_END;

        // ---- phase 4: quad(1,0) — stage (t+2).A1 into A1 (freed at phase 3) ----
        read_bf(bfr, Lb + brow, sl0, sl1);
        STG(pA1, dA, bufb + 16384, st2);
        PH_MID;
        quad_mfma<1, 0>(acc, af, bfr);
        PH_END_VM;   // vmcnt(6): (t+1) fully landed; 3 half-tiles in flight
    }
    asm volatile("s_waitcnt vmcnt(0)" ::: "memory");   // drain before LDS teardown
#undef STG
}

// hidden = relu(Acat @ Bt1^T + bias2[b]) -> bf16  (exact R2 kernel)
__global__ __launch_bounds__(512, 2) void mfma_ff1_k(const u16* __restrict__ Acat,
                                                     const u16* __restrict__ Bt1,
                                                     const float* __restrict__ bias2,
                                                     u16* __restrict__ H) {
    __shared__ __align__(16) char lds[131072];
    f32x4 acc[2][2][4][2] = {};
    int bid = blockIdx.x;                 // 256 blocks, nwg%8==0 -> bijective XCD swizzle
    int x = bid & 7, j = bid >> 3;
    int nt = j & 3, mt = (j >> 2) * 8 + x;
    int bm = mt * 256, bn = nt * 256;
    mfma256_core(Acat, 2048, Bt1, 2048, 2048, bm, bn, (lds_char*)lds, acc);
    const int lane = threadIdx.x & 63, wave = threadIdx.x >> 6;
    const int wm = wave >> 2, wn = wave & 3;
    int rbase = bm + wm * 64 + (lane >> 4) * 4;
    int cbase = bn + wn * 32 + (lane & 15);
    int bb = bm >> 12;
#pragma unroll
    for (int mh = 0; mh < 2; ++mh)
#pragma unroll
        for (int nh = 0; nh < 2; ++nh)
#pragma unroll
            for (int mi = 0; mi < 4; ++mi)
#pragma unroll
                for (int ni = 0; ni < 2; ++ni) {
                    int col = cbase + nh * 128 + ni * 16;
                    float bz = bias2[bb * 1024 + col];
                    int row0 = rbase + mh * 128 + mi * 16;
#pragma unroll
                    for (int r = 0; r < 4; ++r) {
                        float v = acc[mh][nh][mi][ni][r] + bz;
                        H[(size_t)(row0 + r) * 1024 + col] = f2bf(fmaxf(v, 0.f));
                    }
                }
}

// P = H @ ff2 + ff2_bias + X(fp32) -> bf16 (exact R2 kernel; P aliases Acat)
__global__ __launch_bounds__(512, 2) void mfma_ff2_k(const u16* __restrict__ H,
                                                     const u16* __restrict__ Bt2,
                                                     const float* __restrict__ ff2b,
                                                     const float* __restrict__ X,
                                                     u16* __restrict__ P) {
    __shared__ __align__(16) char lds[131072];
    f32x4 acc[2][2][4][2] = {};
    int bid = blockIdx.x;
    int x = bid & 7, j = bid >> 3;
    int nt = j & 3, mt = (j >> 2) * 8 + x;
    int bm = mt * 256, bn = nt * 256;
    mfma256_core(H, 1024, Bt2, 1024, 1024, bm, bn, (lds_char*)lds, acc);
    const int lane = threadIdx.x & 63, wave = threadIdx.x >> 6;
    const int wm = wave >> 2, wn = wave & 3;
    int rbase = bm + wm * 64 + (lane >> 4) * 4;
    int cbase = bn + wn * 32 + (lane & 15);
#pragma unroll
    for (int mh = 0; mh < 2; ++mh)
#pragma unroll
        for (int nh = 0; nh < 2; ++nh)
#pragma unroll
            for (int mi = 0; mi < 4; ++mi)
#pragma unroll
                for (int ni = 0; ni < 2; ++ni) {
                    int col = cbase + nh * 128 + ni * 16;
                    float bz = ff2b[col];
                    int row0 = rbase + mh * 128 + mi * 16;
#pragma unroll
                    for (int r = 0; r < 4; ++r) {
                        size_t off = (size_t)(row0 + r) * 1024 + col;
                        P[off] = f2bf(acc[mh][nh][mi][ni][r] + bz + X[off]);
                    }
                }
}

// ================= LayerNorm over bf16 P -> fp32 out (exact R2 kernel) =================
__global__ __launch_bounds__(256) void ln_k(const u16* __restrict__ P,
                                            const float* __restrict__ gam,
                                            const float* __restrict__ bet,
                                            float* __restrict__ out) {
    __shared__ float sbuf[4];
    int row = blockIdx.x;
    int tid = threadIdx.x;
    const u16* pr = P + (size_t)row * DD + tid * 4;
    float x0 = bf2f(pr[0]), x1 = bf2f(pr[1]), x2 = bf2f(pr[2]), x3 = bf2f(pr[3]);
    float local = x0 + x1 + x2 + x3;
    #pragma unroll
    for (int o = 32; o > 0; o >>= 1) local += __shfl_down(local, o, 64);
    if ((tid & 63) == 0) sbuf[tid >> 6] = local;
    __syncthreads();
    float mu = (sbuf[0] + sbuf[1] + sbuf[2] + sbuf[3]) * (1.0f / 1024.0f);
    __syncthreads();
    float d0 = x0 - mu, d1 = x1 - mu, d2 = x2 - mu, d3 = x3 - mu;
    float v2 = d0 * d0 + d1 * d1 + d2 * d2 + d3 * d3;
    #pragma unroll
    for (int o = 32; o > 0; o >>= 1) v2 += __shfl_down(v2, o, 64);
    if ((tid & 63) == 0) sbuf[tid >> 6] = v2;
    __syncthreads();
    float var = (sbuf[0] + sbuf[1] + sbuf[2] + sbuf[3]) * (1.0f / 1024.0f);
    float rs = rsqrtf(var + 1e-6f);
    float4 gg = *(const float4*)&gam[tid * 4];
    float4 bb = *(const float4*)&bet[tid * 4];
    float4 o4;
    o4.x = d0 * rs * gg.x + bb.x;
    o4.y = d1 * rs * gg.y + bb.y;
    o4.z = d2 * rs * gg.z + bb.z;
    o4.w = d3 * rs * gg.w + bb.w;
    *(float4*)&out[(size_t)row * DD + tid * 4] = o4;
}

extern "C" void kernel_launch(void* const* d_in, const int* in_sizes, int n_in,
                              void* d_out, int out_size, void* d_ws, size_t ws_size,
                              hipStream_t stream) {
    const float* X      = (const float*)d_in[0];
    const float* vec    = (const float*)d_in[1];
    // d_in[2] attention_weights, d_in[3] temperature: numerically dead (eps=1e-30 rounds away in fp32)
    const float* values = (const float*)d_in[4];
    const float* oper   = (const float*)d_in[5];
    const float* ff1    = (const float*)d_in[6];
    const float* ff1b   = (const float*)d_in[7];
    const float* ff2    = (const float*)d_in[8];
    const float* ff2b   = (const float*)d_in[9];
    const float* gam    = (const float*)d_in[10];
    const float* bet    = (const float*)d_in[11];
    float* out = (float*)d_out;

    char* w = (char*)d_ws;
    u16*   Acat  = (u16*)w;                                  // 64 MB (16384x2048)
    u16*   Pbf   = (u16*)w;                                  // alias: Acat dead when P written
    u16*   Hbf   = (u16*)(w + (size_t)(64u << 20));          // 32 MB
    u16*   Vbf   = (u16*)(w + (size_t)(96u << 20));          // 2 MB
    u16*   OpT   = (u16*)(w + (size_t)(98u << 20));          // 2 MB
    u16*   FbT   = (u16*)(w + (size_t)(100u << 20));         // 2 MB
    u16*   WvBf  = (u16*)(w + (size_t)(102u << 20));         // 2 MB
    u16*   Bt1   = (u16*)(w + (size_t)(104u << 20));         // 4 MB (1024x2048)
    u16*   Bt2   = (u16*)(w + (size_t)(108u << 20));         // 2 MB
    float* bias2 = (float*)(w + (size_t)(110u << 20));       // 16 KB
    float* csum  = (float*)(w + (size_t)(110u << 20) + (1u << 16)); // 512 KB

    // 1) fused prep: converts, transposes, chunk_sum, bias2
    prep_k<<<5664, 256, 0, stream>>>(X, vec, values, oper, ff1, ff1b, ff2,
                                     Vbf, OpT, FbT, Bt1, Bt2, csum, bias2);
    // 2) chunk-prefix || Wv = values @ operator
    k2_k<<<272, 256, 0, stream>>>(csum, Vbf, OpT, WvBf);
    // 3) Acat pack || W2 -> Bt1 high half
    k3_k<<<512, 256, 0, stream>>>(X, csum, Acat, FbT, WvBf, Bt1);
    // 4) hidden = relu([X|M] @ [W1;W2]^T + bias2)
    mfma_ff1_k<<<256, 512, 0, stream>>>(Acat, Bt1, bias2, Hbf);
    // 5) P = hidden @ ff2^T + ff2b + X
    mfma_ff2_k<<<256, 512, 0, stream>>>(Hbf, Bt2, ff2b, X, Pbf);
    // 6) LayerNorm
    ln_k<<<BB * SS, 256, 0, stream>>>(Pbf, gam, bet, out);
}